// Round 1
// baseline (2147.476 us; speedup 1.0000x reference)
//
#include <hip/hip_runtime.h>
#include <math.h>

#define BB 512
#define LL 1024
#define EMB 4
#define CC 64
#define HID 64
#define NTF 200
#define TT 247      // seq len after conv1
#define LP 254      // after pool
#define D2 128
#define G4 256      // 4*H

__device__ __forceinline__ float sigf(float x) { return 1.0f / (1.0f + __expf(-x)); }

// ---------------- K1: conv0 + BN + ReLU + maxpool(4) ----------------
__global__ __launch_bounds__(256) void k_conv0(const float* __restrict__ x,
    const float* __restrict__ w0, const float* __restrict__ b0,
    const float* __restrict__ g0, const float* __restrict__ be0,
    const float* __restrict__ m0, const float* __restrict__ v0,
    float* __restrict__ p)
{
  int b = blockIdx.x;
  int t0 = blockIdx.y * 64;
  __shared__ float4 xs[264];         // x[b, 4*t0 .. 4*t0+263, 0:4]
  __shared__ float wsm[64 * 33];     // padded stride 33: [c][e*8+k]
  __shared__ float sc[64], sb[64];
  int tid = threadIdx.x;
  for (int j = tid; j < 264; j += 256) {
    int l = t0 * 4 + j;
    xs[j] = (l < LL) ? *(const float4*)(x + ((size_t)b * LL + l) * EMB)
                     : make_float4(0.f, 0.f, 0.f, 0.f);
  }
  for (int j = tid; j < 64 * 32; j += 256) {
    int c = j >> 5, r = j & 31;
    wsm[c * 33 + r] = w0[j];
  }
  if (tid < 64) {
    float s = g0[tid] * rsqrtf(v0[tid] + 1e-5f);
    sc[tid] = s;
    sb[tid] = (b0[tid] - m0[tid]) * s + be0[tid];
  }
  __syncthreads();
  int c = tid & 63, tq = tid >> 6;
  float scc = sc[c], sbc = sb[c];
  for (int i = 0; i < 16; ++i) {
    int tl = tq + 4 * i;
    int t = t0 + tl;
    if (t >= LP) break;
    float accp[4] = {0.f, 0.f, 0.f, 0.f};
    #pragma unroll
    for (int k = 0; k < 8; ++k) {
      float wk0 = wsm[c * 33 + 0 * 8 + k];
      float wk1 = wsm[c * 33 + 1 * 8 + k];
      float wk2 = wsm[c * 33 + 2 * 8 + k];
      float wk3 = wsm[c * 33 + 3 * 8 + k];
      #pragma unroll
      for (int pp = 0; pp < 4; ++pp) {
        float4 xv = xs[4 * tl + pp + k];
        accp[pp] += xv.x * wk0 + xv.y * wk1 + xv.z * wk2 + xv.w * wk3;
      }
    }
    float mx = -1e30f;
    #pragma unroll
    for (int pp = 0; pp < 4; ++pp) mx = fmaxf(mx, accp[pp] * scc + sbc);
    p[((size_t)b * CC + c) * LP + t] = fmaxf(mx, 0.0f);
  }
}

// ---------------- K2: conv1 + BN + ReLU -> x2[b][t][c] ----------------
__global__ __launch_bounds__(256) void k_conv1(const float* __restrict__ p,
    const float* __restrict__ w1, const float* __restrict__ b1,
    const float* __restrict__ g1, const float* __restrict__ be1,
    const float* __restrict__ m1, const float* __restrict__ v1,
    float* __restrict__ x2)
{
  int b = blockIdx.x;
  int t0 = blockIdx.y * 64;
  __shared__ float ps[16 * 71];
  __shared__ float wsm[64 * 129];    // padded stride 129: [c][ii*8+k]
  __shared__ float sc[64], sb[64];
  int tid = threadIdx.x;
  if (tid < 64) {
    float s = g1[tid] * rsqrtf(v1[tid] + 1e-5f);
    sc[tid] = s;
    sb[tid] = (b1[tid] - m1[tid]) * s + be1[tid];
  }
  int c = tid & 63, tq = tid >> 6;
  float acc[16];
  #pragma unroll
  for (int i = 0; i < 16; ++i) acc[i] = 0.0f;
  for (int ci0 = 0; ci0 < 64; ci0 += 16) {
    __syncthreads();
    for (int j = tid; j < 16 * 71; j += 256) {
      int ii = j / 71, jj = j - ii * 71;
      int t = t0 + jj;
      ps[j] = (t < LP) ? p[((size_t)b * CC + ci0 + ii) * LP + t] : 0.0f;
    }
    for (int j = tid; j < 64 * 128; j += 256) {
      int cc2 = j >> 7, r = j & 127;
      wsm[cc2 * 129 + r] = w1[(size_t)cc2 * 512 + ci0 * 8 + r];
    }
    __syncthreads();
    #pragma unroll
    for (int i = 0; i < 16; ++i) {
      int tl = tq + 4 * i;
      float a = acc[i];
      #pragma unroll
      for (int ii = 0; ii < 16; ++ii) {
        #pragma unroll
        for (int k = 0; k < 8; ++k)
          a += ps[ii * 71 + tl + k] * wsm[c * 129 + ii * 8 + k];
      }
      acc[i] = a;
    }
  }
  float scc = sc[c], sbc = sb[c];
  for (int i = 0; i < 16; ++i) {
    int t = t0 + tq + 4 * i;
    if (t < TT) x2[((size_t)b * TT + t) * CC + c] = fmaxf(acc[i] * scc + sbc, 0.0f);
  }
}

// ---------------- K3: bidirectional LSTM, one block per (b, dir) ----------------
__global__ __launch_bounds__(256) void k_lstm(const float* __restrict__ x2,
    const float* __restrict__ wih_f, const float* __restrict__ whh_f,
    const float* __restrict__ bih_f, const float* __restrict__ bhh_f,
    const float* __restrict__ wih_b, const float* __restrict__ whh_b,
    const float* __restrict__ bih_b, const float* __restrict__ bhh_b,
    float* __restrict__ values, float* __restrict__ hT)
{
  int b = blockIdx.x;
  int dir = blockIdx.y;
  int tid = threadIdx.x;
  const float* wih = dir ? wih_b : wih_f;
  const float* whh = dir ? whh_b : whh_f;
  const float* bih = dir ? bih_b : bih_f;
  const float* bhh = dir ? bhh_b : bhh_f;
  __shared__ float4 xb4[16];
  __shared__ float4 hb4[16];
  __shared__ float gl[256];
  float* xb = (float*)xb4;
  float* hb = (float*)hb4;
  float4 wi[16], wh[16];
  const float4* wip = (const float4*)(wih + (size_t)tid * 64);
  const float4* whp = (const float4*)(whh + (size_t)tid * 64);
  #pragma unroll
  for (int j = 0; j < 16; ++j) { wi[j] = wip[j]; wh[j] = whp[j]; }
  float bias = bih[tid] + bhh[tid];
  float cst = 0.0f;
  if (tid < 64) hb[tid] = 0.0f;
  for (int s = 0; s < TT; ++s) {
    int t = dir ? (TT - 1 - s) : s;
    if (tid < 64) xb[tid] = x2[((size_t)b * TT + t) * CC + tid];
    __syncthreads();
    float a = bias;
    #pragma unroll
    for (int j = 0; j < 16; ++j) {
      float4 xv = xb4[j];
      a += xv.x * wi[j].x + xv.y * wi[j].y + xv.z * wi[j].z + xv.w * wi[j].w;
    }
    #pragma unroll
    for (int j = 0; j < 16; ++j) {
      float4 hv = hb4[j];
      a += hv.x * wh[j].x + hv.y * wh[j].y + hv.z * wh[j].z + hv.w * wh[j].w;
    }
    gl[tid] = a;
    __syncthreads();
    if (tid < 64) {
      float ig = sigf(gl[tid]);
      float fg = sigf(gl[64 + tid]);
      float gg = tanhf(gl[128 + tid]);
      float og = sigf(gl[192 + tid]);
      cst = fg * cst + ig * gg;
      float h = og * tanhf(cst);
      hb[tid] = h;
      values[((size_t)b * TT + t) * D2 + dir * 64 + tid] = h;
      if (s == TT - 1) hT[((size_t)dir * BB + b) * 64 + tid] = h;
    }
  }
}

// ---------------- K3b: q2 = h_n @ W2^T + W2_b ----------------
__global__ __launch_bounds__(128) void k_q2(const float* __restrict__ hT,
    const float* __restrict__ W2, const float* __restrict__ W2b,
    float* __restrict__ q2)
{
  int b = blockIdx.x;
  int tid = threadIdx.x;
  __shared__ float4 hn4[32];
  ((float*)hn4)[tid] = hT[(size_t)b * 128 + tid];
  __syncthreads();
  const float4* w4 = (const float4*)(W2 + (size_t)tid * 128);
  float a = W2b[tid];
  #pragma unroll
  for (int j = 0; j < 32; ++j) {
    float4 w = w4[j]; float4 h = hn4[j];
    a += w.x * h.x + w.y * h.y + w.z * h.z + w.w * h.w;
  }
  q2[(size_t)b * 128 + tid] = a;
}

// ---------------- K4: score = tanh(values@W1^T + W1b + q2) @ V^T + Vb ----------------
__global__ __launch_bounds__(256) void k_score(const float* __restrict__ values,
    const float* __restrict__ W1, const float* __restrict__ W1b,
    const float* __restrict__ q2,
    const float* __restrict__ Vw, const float* __restrict__ Vb,
    float* __restrict__ score)
{
  int b = blockIdx.x;
  int t0 = blockIdx.y * 32;
  int tid = threadIdx.x;
  __shared__ float vs[32 * 128];
  __shared__ float us[32 * 128];
  for (int j = tid; j < 32 * 128; j += 256) {
    int tl = j >> 7, d = j & 127;
    int t = t0 + tl;
    vs[j] = (t < TT) ? values[((size_t)b * TT + t) * D2 + d] : 0.0f;
  }
  __syncthreads();
  {
    int d = tid & 127, th = tid >> 7;
    float base = W1b[d] + q2[(size_t)b * 128 + d];
    float acc[16];
    #pragma unroll
    for (int i = 0; i < 16; ++i) acc[i] = 0.0f;
    const float4* w4 = (const float4*)(W1 + (size_t)d * 128);
    for (int k4 = 0; k4 < 32; ++k4) {
      float4 w = w4[k4];
      #pragma unroll
      for (int i = 0; i < 16; ++i) {
        int tl = th + 2 * i;
        float4 v = *(const float4*)(vs + tl * 128 + k4 * 4);
        acc[i] += v.x * w.x + v.y * w.y + v.z * w.z + v.w * w.w;
      }
    }
    #pragma unroll
    for (int i = 0; i < 16; ++i) {
      int tl = th + 2 * i;
      us[tl * 128 + d] = tanhf(acc[i] + base);
    }
  }
  __syncthreads();
  if (tid < NTF) {
    int n = tid;
    float acc[32];
    #pragma unroll
    for (int i = 0; i < 32; ++i) acc[i] = 0.0f;
    const float4* v4 = (const float4*)(Vw + (size_t)n * 128);
    for (int k4 = 0; k4 < 32; ++k4) {
      float4 w = v4[k4];
      #pragma unroll
      for (int tl = 0; tl < 32; ++tl) {
        float4 u = *(const float4*)(us + tl * 128 + k4 * 4);
        acc[tl] += u.x * w.x + u.y * w.y + u.z * w.z + u.w * w.w;
      }
    }
    float vb = Vb[n];
    for (int tl = 0; tl < 32; ++tl) {
      int t = t0 + tl;
      if (t < TT) score[((size_t)b * TT + t) * NTF + n] = acc[tl] + vb;
    }
  }
}

// ---------------- K5: softmax over t (stores unnormalized exp + 1/sum) ----------------
__global__ __launch_bounds__(256) void k_softmax(float* __restrict__ score,
    float* __restrict__ sinv)
{
  int b = blockIdx.x;
  int n = threadIdx.x;
  if (n >= NTF) return;
  size_t base = (size_t)b * TT * NTF + n;
  float m = -1e30f;
  for (int t = 0; t < TT; ++t) m = fmaxf(m, score[base + (size_t)t * NTF]);
  float s = 0.0f;
  for (int t = 0; t < TT; ++t) {
    float e = __expf(score[base + (size_t)t * NTF] - m);
    score[base + (size_t)t * NTF] = e;
    s += e;
  }
  sinv[(size_t)b * NTF + n] = 1.0f / s;
}

// ---------------- K6: context[b][n][d] = (sum_t e[t,n] * values[t,d]) * sinv ----------------
__global__ __launch_bounds__(256) void k_context(const float* __restrict__ values,
    const float* __restrict__ score, const float* __restrict__ sinv,
    float* __restrict__ ctx)
{
  int b = blockIdx.x;
  int n0 = blockIdx.y * 16;
  int tid = threadIdx.x;
  __shared__ float vls[32 * 128];
  __shared__ float als[32 * 16];
  int nl = tid >> 4, dg = tid & 15;
  float acc[8];
  #pragma unroll
  for (int i = 0; i < 8; ++i) acc[i] = 0.0f;
  for (int tc = 0; tc < TT; tc += 32) {
    __syncthreads();
    for (int j = tid; j < 32 * 128; j += 256) {
      int tl = j >> 7, d = j & 127;
      int t = tc + tl;
      vls[j] = (t < TT) ? values[((size_t)b * TT + t) * D2 + d] : 0.0f;
    }
    for (int j = tid; j < 512; j += 256) {
      int tl = j >> 4, nn = j & 15;
      int t = tc + tl, n = n0 + nn;
      als[j] = (t < TT && n < NTF) ? score[((size_t)b * TT + t) * NTF + n] : 0.0f;
    }
    __syncthreads();
    #pragma unroll
    for (int tl = 0; tl < 32; ++tl) {
      float a = als[tl * 16 + nl];
      const float4* v4 = (const float4*)(vls + tl * 128 + dg * 8);
      float4 v0 = v4[0], v1 = v4[1];
      acc[0] += a * v0.x; acc[1] += a * v0.y; acc[2] += a * v0.z; acc[3] += a * v0.w;
      acc[4] += a * v1.x; acc[5] += a * v1.y; acc[6] += a * v1.z; acc[7] += a * v1.w;
    }
  }
  int n = n0 + nl;
  if (n < NTF) {
    float rs = sinv[(size_t)b * NTF + n];
    float4 o0 = make_float4(acc[0] * rs, acc[1] * rs, acc[2] * rs, acc[3] * rs);
    float4 o1 = make_float4(acc[4] * rs, acc[5] * rs, acc[6] * rs, acc[7] * rs);
    float4* op = (float4*)(ctx + ((size_t)b * NTF + n) * D2 + dg * 8);
    op[0] = o0; op[1] = o1;
  }
}

// ---------------- K7: per-TF heads ----------------
__global__ __launch_bounds__(256) void k_heads(const float* __restrict__ ctx,
    const float* __restrict__ fc1w, const float* __restrict__ fc1b,
    const float* __restrict__ fc2w, const float* __restrict__ fc2b,
    float* __restrict__ out)
{
  int n = blockIdx.x;
  int bq = blockIdx.y;
  int tid = threadIdx.x;
  int o = tid & 63, w = tid >> 6;
  __shared__ float ctxs[4 * 128];
  float4 fr[32];
  const float4* fp = (const float4*)(fc1w + ((size_t)n * 64 + o) * 128);
  #pragma unroll
  for (int j = 0; j < 32; ++j) fr[j] = fp[j];
  float f1bv = fc1b[n * 64 + o];
  float f2 = fc2w[n * 64 + o];
  float f2b = fc2b[n];
  for (int i = 0; i < 16; ++i) {
    int bbase = bq * 64 + i * 4;
    __syncthreads();
    for (int j = tid; j < 512; j += 256) {
      int ww = j >> 7, k = j & 127;
      ctxs[j] = ctx[((size_t)(bbase + ww) * NTF + n) * D2 + k];
    }
    __syncthreads();
    float a = f1bv;
    const float4* c4 = (const float4*)(ctxs + w * 128);
    #pragma unroll
    for (int j = 0; j < 32; ++j) {
      float4 cv = c4[j];
      float4 fv = fr[j];
      a += cv.x * fv.x + cv.y * fv.y + cv.z * fv.z + cv.w * fv.w;
    }
    float part = fmaxf(a, 0.0f) * f2;
    #pragma unroll
    for (int off = 32; off > 0; off >>= 1)
      part += __shfl_down(part, off, 64);
    if (o == 0) out[(size_t)(bbase + w) * NTF + n] = part + f2b;
  }
}

extern "C" void kernel_launch(void* const* d_in, const int* in_sizes, int n_in,
                              void* d_out, int out_size, void* d_ws, size_t ws_size,
                              hipStream_t stream)
{
  const float* x    = (const float*)d_in[0];
  const float* c0w  = (const float*)d_in[1];
  const float* c0b  = (const float*)d_in[2];
  const float* g0   = (const float*)d_in[3];
  const float* be0  = (const float*)d_in[4];
  const float* m0   = (const float*)d_in[5];
  const float* v0   = (const float*)d_in[6];
  const float* c1w  = (const float*)d_in[7];
  const float* c1b  = (const float*)d_in[8];
  const float* g1   = (const float*)d_in[9];
  const float* be1  = (const float*)d_in[10];
  const float* m1   = (const float*)d_in[11];
  const float* v1   = (const float*)d_in[12];
  const float* wihf = (const float*)d_in[13];
  const float* whhf = (const float*)d_in[14];
  const float* bihf = (const float*)d_in[15];
  const float* bhhf = (const float*)d_in[16];
  const float* wihb = (const float*)d_in[17];
  const float* whhb = (const float*)d_in[18];
  const float* bihb = (const float*)d_in[19];
  const float* bhhb = (const float*)d_in[20];
  const float* W1w  = (const float*)d_in[21];
  const float* W1b  = (const float*)d_in[22];
  const float* W2w  = (const float*)d_in[23];
  const float* W2b  = (const float*)d_in[24];
  const float* Vw   = (const float*)d_in[25];
  const float* Vb   = (const float*)d_in[26];
  const float* f1w  = (const float*)d_in[27];
  const float* f1b  = (const float*)d_in[28];
  const float* f2w  = (const float*)d_in[29];
  const float* f2b  = (const float*)d_in[30];

  float* ws = (float*)d_ws;
  // region layout (floats). score overlaps p/x2 (both dead before K4 writes score).
  float* score  = ws;                    // 512*247*200 = 25,292,800
  float* p      = ws;                    // 512*64*254  =  8,323,072
  float* x2     = ws + 8323072;          // 512*247*64  =  8,093,696 (ends 16,416,768)
  float* values = ws + 25292800;         // 512*247*128 = 16,187,392
  float* hT     = ws + 41480192;         // 2*512*64    =     65,536
  float* q2     = ws + 41545728;         // 512*128     =     65,536
  float* sinv   = ws + 41611264;         // 512*200     =    102,400
  float* ctx    = ws + 41713664;         // 512*200*128 = 13,107,200 (end 54,820,864 floats = 219.3 MB)
  float* out    = (float*)d_out;

  k_conv0<<<dim3(BB, 4), 256, 0, stream>>>(x, c0w, c0b, g0, be0, m0, v0, p);
  k_conv1<<<dim3(BB, 4), 256, 0, stream>>>(p, c1w, c1b, g1, be1, m1, v1, x2);
  k_lstm<<<dim3(BB, 2), 256, 0, stream>>>(x2, wihf, whhf, bihf, bhhf,
                                          wihb, whhb, bihb, bhhb, values, hT);
  k_q2<<<dim3(BB), 128, 0, stream>>>(hT, W2w, W2b, q2);
  k_score<<<dim3(BB, 8), 256, 0, stream>>>(values, W1w, W1b, q2, Vw, Vb, score);
  k_softmax<<<dim3(BB), 256, 0, stream>>>(score, sinv);
  k_context<<<dim3(BB, 13), 256, 0, stream>>>(values, score, sinv, ctx);
  k_heads<<<dim3(NTF, 8), 256, 0, stream>>>(ctx, f1w, f1b, f2w, f2b, out);
}

// Round 2
// 1596.283 us; speedup vs baseline: 1.3453x; 1.3453x over previous
//
#include <hip/hip_runtime.h>
#include <math.h>

#define BB 512
#define LL 1024
#define EMB 4
#define CC 64
#define NTF 200
#define TT 247      // seq len after conv1
#define LP 254      // after pool
#define D2 128

typedef __attribute__((ext_vector_type(8))) short short8;
typedef __attribute__((ext_vector_type(4))) float f32x4;
typedef __attribute__((ext_vector_type(4))) unsigned int uint4v;

__device__ __forceinline__ float sigf(float x) { return 1.0f / (1.0f + __expf(-x)); }

// f32 -> bf16 round-to-nearest-even (finite inputs)
__device__ __forceinline__ unsigned short bfr(float f) {
  unsigned u = __builtin_bit_cast(unsigned, f);
  u += 0x7fffu + ((u >> 16) & 1u);
  return (unsigned short)(u >> 16);
}

// ---------------- K0: convert conv weights to bf16 in ws ----------------
__global__ __launch_bounds__(256) void k_cvtw(const float* __restrict__ w0,
    const float* __restrict__ w1,
    unsigned short* __restrict__ wbf0, unsigned short* __restrict__ wbf1)
{
  int i = blockIdx.x * 256 + threadIdx.x;   // grid 128*256 = 32768
  if (i < 2048) wbf0[i] = bfr(w0[i]);
  wbf1[i] = bfr(w1[i]);
}

// ---------------- K1: conv0 + BN + ReLU + maxpool(4), MFMA ----------------
// out p[b][t][c], t<254. A[l][e*8+k] = x[b][l+k][e]; B[n=co][kidx] = w0 row.
__global__ __launch_bounds__(256) void k_conv0m(const float* __restrict__ x,
    const unsigned short* __restrict__ wbf0,
    const float* __restrict__ b0, const float* __restrict__ g0,
    const float* __restrict__ be0, const float* __restrict__ m0,
    const float* __restrict__ v0, float* __restrict__ p)
{
  int b = blockIdx.x, l0 = blockIdx.y * 64;
  __shared__ float xs[71 * 4];
  __shared__ float sc[64], sb[64];
  int tid = threadIdx.x;
  for (int j = tid; j < 71; j += 256) {
    int l = l0 + j;
    float4 xv = (l < LL) ? *(const float4*)(x + ((size_t)b * LL + l) * EMB)
                         : make_float4(0.f, 0.f, 0.f, 0.f);
    *(float4*)(xs + j * 4) = xv;
  }
  if (tid < 64) {
    float s = g0[tid] * rsqrtf(v0[tid] + 1e-5f);
    sc[tid] = s;
    sb[tid] = (b0[tid] - m0[tid]) * s + be0[tid];
  }
  __syncthreads();
  int w = tid >> 6, lane = tid & 63, nl = lane & 15, quad = lane >> 4;
  const float* ap = xs + (w * 16 + nl) * 4 + quad;   // A[m][quad*8+j] = x[l0+m+j][quad]
  short8 af;
  #pragma unroll
  for (int j = 0; j < 8; ++j) af[j] = (short)bfr(ap[j * 4]);
  f32x4 acc[4];
  #pragma unroll
  for (int nt = 0; nt < 4; ++nt) {
    short8 bf = __builtin_bit_cast(short8,
        *(const uint4v*)(wbf0 + ((nt * 16 + nl) * 32 + quad * 8)));
    acc[nt] = (f32x4){0.f, 0.f, 0.f, 0.f};
    acc[nt] = __builtin_amdgcn_mfma_f32_16x16x32_bf16(af, bf, acc[nt], 0, 0, 0);
  }
  // D row m = quad*4+reg -> l = l0 + w*16 + quad*4 + reg: 4 consecutive l = 1 pool group
  int t = (l0 >> 2) + w * 4 + quad;
  if (t < LP) {
    #pragma unroll
    for (int nt = 0; nt < 4; ++nt) {
      int c = nt * 16 + nl;
      float scc = sc[c], sbc = sb[c];
      float mx = -1e30f;
      #pragma unroll
      for (int r = 0; r < 4; ++r) mx = fmaxf(mx, acc[nt][r] * scc + sbc);
      p[((size_t)b * LP + t) * CC + c] = fmaxf(mx, 0.0f);
    }
  }
}

// ---------------- K2: conv1 + BN + ReLU -> x2[b][t][c], MFMA ----------------
// GEMM: M=t(64/block), N=64 co, K=512 (ci*8+k). A[t][ci*8+k] = p[b][t+k][ci].
__global__ __launch_bounds__(256) void k_conv1m(const float* __restrict__ p,
    const unsigned short* __restrict__ wbf1,
    const float* __restrict__ b1, const float* __restrict__ g1,
    const float* __restrict__ be1, const float* __restrict__ m1,
    const float* __restrict__ v1, float* __restrict__ x2)
{
  int b = blockIdx.x, t0 = blockIdx.y * 64;
  __shared__ float As[71 * 68];   // [col=t-local][ci], stride 68 -> 2-way banks (free)
  __shared__ float sc[64], sb[64];
  int tid = threadIdx.x;
  for (int j = tid; j < 71 * 64; j += 256) {
    int col = j >> 6, ci = j & 63;
    int t = t0 + col;
    As[col * 68 + ci] = (t < LP) ? p[((size_t)b * LP + t) * CC + ci] : 0.0f;
  }
  if (tid < 64) {
    float s = g1[tid] * rsqrtf(v1[tid] + 1e-5f);
    sc[tid] = s;
    sb[tid] = (b1[tid] - m1[tid]) * s + be1[tid];
  }
  __syncthreads();
  int w = tid >> 6, lane = tid & 63, nl = lane & 15, quad = lane >> 4;
  const float* ap = As + (w * 16 + nl) * 68;
  f32x4 acc[4];
  #pragma unroll
  for (int nt = 0; nt < 4; ++nt) acc[nt] = (f32x4){0.f, 0.f, 0.f, 0.f};
  for (int ks = 0; ks < 16; ++ks) {
    int ci = ks * 4 + quad;                 // k = ci*8 + j
    short8 af;
    #pragma unroll
    for (int j = 0; j < 8; ++j) af[j] = (short)bfr(ap[j * 68 + ci]);
    #pragma unroll
    for (int nt = 0; nt < 4; ++nt) {
      short8 bf = __builtin_bit_cast(short8,
          *(const uint4v*)(wbf1 + ((size_t)(nt * 16 + nl) * 512 + ci * 8)));
      acc[nt] = __builtin_amdgcn_mfma_f32_16x16x32_bf16(af, bf, acc[nt], 0, 0, 0);
    }
  }
  #pragma unroll
  for (int nt = 0; nt < 4; ++nt) {
    int c = nt * 16 + nl;
    float scc = sc[c], sbc = sb[c];
    #pragma unroll
    for (int r = 0; r < 4; ++r) {
      int t = t0 + w * 16 + quad * 4 + r;
      if (t < TT) x2[((size_t)b * TT + t) * CC + c] = fmaxf(acc[nt][r] * scc + sbc, 0.0f);
    }
  }
}

// ---------------- K3: bidirectional LSTM, one block per (b, dir) ----------------
__global__ __launch_bounds__(256) void k_lstm(const float* __restrict__ x2,
    const float* __restrict__ wih_f, const float* __restrict__ whh_f,
    const float* __restrict__ bih_f, const float* __restrict__ bhh_f,
    const float* __restrict__ wih_b, const float* __restrict__ whh_b,
    const float* __restrict__ bih_b, const float* __restrict__ bhh_b,
    float* __restrict__ values, float* __restrict__ hT)
{
  int b = blockIdx.x;
  int dir = blockIdx.y;
  int tid = threadIdx.x;
  const float* wih = dir ? wih_b : wih_f;
  const float* whh = dir ? whh_b : whh_f;
  const float* bih = dir ? bih_b : bih_f;
  const float* bhh = dir ? bhh_b : bhh_f;
  __shared__ float4 xb4[16];
  __shared__ float4 hb4[16];
  __shared__ float gl[256];
  float* xb = (float*)xb4;
  float* hb = (float*)hb4;
  float4 wi[16], wh[16];
  const float4* wip = (const float4*)(wih + (size_t)tid * 64);
  const float4* whp = (const float4*)(whh + (size_t)tid * 64);
  #pragma unroll
  for (int j = 0; j < 16; ++j) { wi[j] = wip[j]; wh[j] = whp[j]; }
  float bias = bih[tid] + bhh[tid];
  float cst = 0.0f;
  if (tid < 64) hb[tid] = 0.0f;
  for (int s = 0; s < TT; ++s) {
    int t = dir ? (TT - 1 - s) : s;
    if (tid < 64) xb[tid] = x2[((size_t)b * TT + t) * CC + tid];
    __syncthreads();
    float a = bias;
    #pragma unroll
    for (int j = 0; j < 16; ++j) {
      float4 xv = xb4[j];
      a += xv.x * wi[j].x + xv.y * wi[j].y + xv.z * wi[j].z + xv.w * wi[j].w;
    }
    #pragma unroll
    for (int j = 0; j < 16; ++j) {
      float4 hv = hb4[j];
      a += hv.x * wh[j].x + hv.y * wh[j].y + hv.z * wh[j].z + hv.w * wh[j].w;
    }
    gl[tid] = a;
    __syncthreads();
    if (tid < 64) {
      float ig = sigf(gl[tid]);
      float fg = sigf(gl[64 + tid]);
      float gg = tanhf(gl[128 + tid]);
      float og = sigf(gl[192 + tid]);
      cst = fg * cst + ig * gg;
      float h = og * tanhf(cst);
      hb[tid] = h;
      values[((size_t)b * TT + t) * D2 + dir * 64 + tid] = h;
      if (s == TT - 1) hT[((size_t)dir * BB + b) * 64 + tid] = h;
    }
  }
}

// ---------------- K3b: q2 = h_n @ W2^T + W2_b ----------------
__global__ __launch_bounds__(128) void k_q2(const float* __restrict__ hT,
    const float* __restrict__ W2, const float* __restrict__ W2b,
    float* __restrict__ q2)
{
  int b = blockIdx.x;
  int tid = threadIdx.x;
  __shared__ float4 hn4[32];
  ((float*)hn4)[tid] = hT[(size_t)b * 128 + tid];
  __syncthreads();
  const float4* w4 = (const float4*)(W2 + (size_t)tid * 128);
  float a = W2b[tid];
  #pragma unroll
  for (int j = 0; j < 32; ++j) {
    float4 w = w4[j]; float4 h = hn4[j];
    a += w.x * h.x + w.y * h.y + w.z * h.z + w.w * h.w;
  }
  q2[(size_t)b * 128 + tid] = a;
}

// ---------------- K4: score = tanh(values@W1^T + W1b + q2) @ V^T + Vb ----------------
__global__ __launch_bounds__(256) void k_score(const float* __restrict__ values,
    const float* __restrict__ W1, const float* __restrict__ W1b,
    const float* __restrict__ q2,
    const float* __restrict__ Vw, const float* __restrict__ Vb,
    float* __restrict__ score)
{
  int b = blockIdx.x;
  int t0 = blockIdx.y * 32;
  int tid = threadIdx.x;
  __shared__ float vs[32 * 128];
  __shared__ float us[32 * 128];
  for (int j = tid; j < 32 * 128; j += 256) {
    int tl = j >> 7, d = j & 127;
    int t = t0 + tl;
    vs[j] = (t < TT) ? values[((size_t)b * TT + t) * D2 + d] : 0.0f;
  }
  __syncthreads();
  {
    int d = tid & 127, th = tid >> 7;
    float base = W1b[d] + q2[(size_t)b * 128 + d];
    float acc[16];
    #pragma unroll
    for (int i = 0; i < 16; ++i) acc[i] = 0.0f;
    const float4* w4 = (const float4*)(W1 + (size_t)d * 128);
    for (int k4 = 0; k4 < 32; ++k4) {
      float4 w = w4[k4];
      #pragma unroll
      for (int i = 0; i < 16; ++i) {
        int tl = th + 2 * i;
        float4 v = *(const float4*)(vs + tl * 128 + k4 * 4);
        acc[i] += v.x * w.x + v.y * w.y + v.z * w.z + v.w * w.w;
      }
    }
    #pragma unroll
    for (int i = 0; i < 16; ++i) {
      int tl = th + 2 * i;
      us[tl * 128 + d] = tanhf(acc[i] + base);
    }
  }
  __syncthreads();
  if (tid < NTF) {
    int n = tid;
    float acc[32];
    #pragma unroll
    for (int i = 0; i < 32; ++i) acc[i] = 0.0f;
    const float4* v4 = (const float4*)(Vw + (size_t)n * 128);
    for (int k4 = 0; k4 < 32; ++k4) {
      float4 w = v4[k4];
      #pragma unroll
      for (int tl = 0; tl < 32; ++tl) {
        float4 u = *(const float4*)(us + tl * 128 + k4 * 4);
        acc[tl] += u.x * w.x + u.y * w.y + u.z * w.z + u.w * w.w;
      }
    }
    float vb = Vb[n];
    for (int tl = 0; tl < 32; ++tl) {
      int t = t0 + tl;
      if (t < TT) score[((size_t)b * TT + t) * NTF + n] = acc[tl] + vb;
    }
  }
}

// ---------------- K5: softmax over t (stores unnormalized exp + 1/sum) ----------------
__global__ __launch_bounds__(256) void k_softmax(float* __restrict__ score,
    float* __restrict__ sinv)
{
  int b = blockIdx.x;
  int n = threadIdx.x;
  if (n >= NTF) return;
  size_t base = (size_t)b * TT * NTF + n;
  float m = -1e30f;
  for (int t = 0; t < TT; ++t) m = fmaxf(m, score[base + (size_t)t * NTF]);
  float s = 0.0f;
  for (int t = 0; t < TT; ++t) {
    float e = __expf(score[base + (size_t)t * NTF] - m);
    score[base + (size_t)t * NTF] = e;
    s += e;
  }
  sinv[(size_t)b * NTF + n] = 1.0f / s;
}

// ---------------- K6: context[b][n][d] = (sum_t e[t,n] * values[t,d]) * sinv ----------------
__global__ __launch_bounds__(256) void k_context(const float* __restrict__ values,
    const float* __restrict__ score, const float* __restrict__ sinv,
    float* __restrict__ ctx)
{
  int b = blockIdx.x;
  int n0 = blockIdx.y * 16;
  int tid = threadIdx.x;
  __shared__ float vls[32 * 128];
  __shared__ float als[32 * 16];
  int nl = tid >> 4, dg = tid & 15;
  float acc[8];
  #pragma unroll
  for (int i = 0; i < 8; ++i) acc[i] = 0.0f;
  for (int tc = 0; tc < TT; tc += 32) {
    __syncthreads();
    for (int j = tid; j < 32 * 128; j += 256) {
      int tl = j >> 7, d = j & 127;
      int t = tc + tl;
      vls[j] = (t < TT) ? values[((size_t)b * TT + t) * D2 + d] : 0.0f;
    }
    for (int j = tid; j < 512; j += 256) {
      int tl = j >> 4, nn = j & 15;
      int t = tc + tl, n = n0 + nn;
      als[j] = (t < TT && n < NTF) ? score[((size_t)b * TT + t) * NTF + n] : 0.0f;
    }
    __syncthreads();
    #pragma unroll
    for (int tl = 0; tl < 32; ++tl) {
      float a = als[tl * 16 + nl];
      const float4* v4 = (const float4*)(vls + tl * 128 + dg * 8);
      float4 v0 = v4[0], v1 = v4[1];
      acc[0] += a * v0.x; acc[1] += a * v0.y; acc[2] += a * v0.z; acc[3] += a * v0.w;
      acc[4] += a * v1.x; acc[5] += a * v1.y; acc[6] += a * v1.z; acc[7] += a * v1.w;
    }
  }
  int n = n0 + nl;
  if (n < NTF) {
    float rs = sinv[(size_t)b * NTF + n];
    float4 o0 = make_float4(acc[0] * rs, acc[1] * rs, acc[2] * rs, acc[3] * rs);
    float4 o1 = make_float4(acc[4] * rs, acc[5] * rs, acc[6] * rs, acc[7] * rs);
    float4* op = (float4*)(ctx + ((size_t)b * NTF + n) * D2 + dg * 8);
    op[0] = o0; op[1] = o1;
  }
}

// ---------------- K7: per-TF heads ----------------
__global__ __launch_bounds__(256) void k_heads(const float* __restrict__ ctx,
    const float* __restrict__ fc1w, const float* __restrict__ fc1b,
    const float* __restrict__ fc2w, const float* __restrict__ fc2b,
    float* __restrict__ out)
{
  int n = blockIdx.x;
  int bq = blockIdx.y;
  int tid = threadIdx.x;
  int o = tid & 63, w = tid >> 6;
  __shared__ float ctxs[4 * 128];
  float4 fr[32];
  const float4* fp = (const float4*)(fc1w + ((size_t)n * 64 + o) * 128);
  #pragma unroll
  for (int j = 0; j < 32; ++j) fr[j] = fp[j];
  float f1bv = fc1b[n * 64 + o];
  float f2 = fc2w[n * 64 + o];
  float f2b = fc2b[n];
  for (int i = 0; i < 16; ++i) {
    int bbase = bq * 64 + i * 4;
    __syncthreads();
    for (int j = tid; j < 512; j += 256) {
      int ww = j >> 7, k = j & 127;
      ctxs[j] = ctx[((size_t)(bbase + ww) * NTF + n) * D2 + k];
    }
    __syncthreads();
    float a = f1bv;
    const float4* c4 = (const float4*)(ctxs + w * 128);
    #pragma unroll
    for (int j = 0; j < 32; ++j) {
      float4 cv = c4[j];
      float4 fv = fr[j];
      a += cv.x * fv.x + cv.y * fv.y + cv.z * fv.z + cv.w * fv.w;
    }
    float part = fmaxf(a, 0.0f) * f2;
    #pragma unroll
    for (int off = 32; off > 0; off >>= 1)
      part += __shfl_down(part, off, 64);
    if (o == 0) out[(size_t)(bbase + w) * NTF + n] = part + f2b;
  }
}

extern "C" void kernel_launch(void* const* d_in, const int* in_sizes, int n_in,
                              void* d_out, int out_size, void* d_ws, size_t ws_size,
                              hipStream_t stream)
{
  const float* x    = (const float*)d_in[0];
  const float* c0w  = (const float*)d_in[1];
  const float* c0b  = (const float*)d_in[2];
  const float* g0   = (const float*)d_in[3];
  const float* be0  = (const float*)d_in[4];
  const float* m0   = (const float*)d_in[5];
  const float* v0   = (const float*)d_in[6];
  const float* c1w  = (const float*)d_in[7];
  const float* c1b  = (const float*)d_in[8];
  const float* g1   = (const float*)d_in[9];
  const float* be1  = (const float*)d_in[10];
  const float* m1   = (const float*)d_in[11];
  const float* v1   = (const float*)d_in[12];
  const float* wihf = (const float*)d_in[13];
  const float* whhf = (const float*)d_in[14];
  const float* bihf = (const float*)d_in[15];
  const float* bhhf = (const float*)d_in[16];
  const float* wihb = (const float*)d_in[17];
  const float* whhb = (const float*)d_in[18];
  const float* bihb = (const float*)d_in[19];
  const float* bhhb = (const float*)d_in[20];
  const float* W1w  = (const float*)d_in[21];
  const float* W1b  = (const float*)d_in[22];
  const float* W2w  = (const float*)d_in[23];
  const float* W2b  = (const float*)d_in[24];
  const float* Vw   = (const float*)d_in[25];
  const float* Vb   = (const float*)d_in[26];
  const float* f1w  = (const float*)d_in[27];
  const float* f1b  = (const float*)d_in[28];
  const float* f2w  = (const float*)d_in[29];
  const float* f2b  = (const float*)d_in[30];

  float* ws = (float*)d_ws;
  // region layout (floats). score overlaps p/x2 (both dead before K4 writes score).
  float* score  = ws;                    // 512*247*200 = 25,292,800
  float* p      = ws;                    // [b][t][c] 512*254*64 = 8,323,072
  float* x2     = ws + 8323072;          // 512*247*64  =  8,093,696
  float* values = ws + 25292800;         // 512*247*128 = 16,187,392
  float* hT     = ws + 41480192;         // 2*512*64
  float* q2     = ws + 41545728;         // 512*128
  float* sinv   = ws + 41611264;         // 512*200
  float* ctx    = ws + 41713664;         // 512*200*128 (ends 54,820,864)
  unsigned short* wbf0 = (unsigned short*)(ws + 54820864);  // 2048 bf16
  unsigned short* wbf1 = wbf0 + 2048;                        // 32768 bf16
  float* out    = (float*)d_out;

  k_cvtw<<<dim3(128), 256, 0, stream>>>(c0w, c1w, wbf0, wbf1);
  k_conv0m<<<dim3(BB, 16), 256, 0, stream>>>(x, wbf0, c0b, g0, be0, m0, v0, p);
  k_conv1m<<<dim3(BB, 4), 256, 0, stream>>>(p, wbf1, c1b, g1, be1, m1, v1, x2);
  k_lstm<<<dim3(BB, 2), 256, 0, stream>>>(x2, wihf, whhf, bihf, bhhf,
                                          wihb, whhb, bihb, bhhb, values, hT);
  k_q2<<<dim3(BB), 128, 0, stream>>>(hT, W2w, W2b, q2);
  k_score<<<dim3(BB, 8), 256, 0, stream>>>(values, W1w, W1b, q2, Vw, Vb, score);
  k_softmax<<<dim3(BB), 256, 0, stream>>>(score, sinv);
  k_context<<<dim3(BB, 13), 256, 0, stream>>>(values, score, sinv, ctx);
  k_heads<<<dim3(NTF, 8), 256, 0, stream>>>(ctx, f1w, f1b, f2w, f2b, out);
}

// Round 3
// 1294.507 us; speedup vs baseline: 1.6589x; 1.2331x over previous
//
#include <hip/hip_runtime.h>
#include <math.h>

#define BB 512
#define LL 1024
#define EMB 4
#define CC 64
#define NTF 200
#define TT 247      // seq len after conv1
#define LP 254      // after pool
#define D2 128

typedef __attribute__((ext_vector_type(8))) short short8;
typedef __attribute__((ext_vector_type(4))) float f32x4;
typedef __attribute__((ext_vector_type(4))) unsigned int uint4v;

__device__ __forceinline__ float sigf(float x) { return 1.0f / (1.0f + __expf(-x)); }
// tanh via exp2-based expf: exact at +-inf saturation
__device__ __forceinline__ float tanhff(float x) {
  return 1.0f - 2.0f / (__expf(2.0f * x) + 1.0f);
}

// f32 -> bf16 round-to-nearest-even (finite inputs)
__device__ __forceinline__ unsigned short bfr(float f) {
  unsigned u = __builtin_bit_cast(unsigned, f);
  u += 0x7fffu + ((u >> 16) & 1u);
  return (unsigned short)(u >> 16);
}

// ---------------- K0: convert weights to bf16 in ws + lstm bias sums ----------------
__global__ __launch_bounds__(256) void k_cvt(const float* __restrict__ w0,
    const float* __restrict__ w1,
    const float* __restrict__ wihf, const float* __restrict__ whhf,
    const float* __restrict__ wihb, const float* __restrict__ whhb,
    const float* __restrict__ bihf, const float* __restrict__ bhhf,
    const float* __restrict__ bihb, const float* __restrict__ bhhb,
    unsigned short* __restrict__ wbf0, unsigned short* __restrict__ wbf1,
    unsigned short* __restrict__ wihbf, unsigned short* __restrict__ whhbf,
    float* __restrict__ lbias)
{
  int i = blockIdx.x * 256 + threadIdx.x;   // grid 128*256 = 32768
  if (i < 2048) wbf0[i] = bfr(w0[i]);
  if (i < 32768) wbf1[i] = bfr(w1[i]);
  if (i < 16384) {
    wihbf[i] = bfr(wihf[i]);
    wihbf[16384 + i] = bfr(wihb[i]);
    whhbf[i] = bfr(whhf[i]);
    whhbf[16384 + i] = bfr(whhb[i]);
  }
  if (i < 256) {
    lbias[i] = bihf[i] + bhhf[i];
    lbias[256 + i] = bihb[i] + bhhb[i];
  }
}

// ---------------- K1: conv0 + BN + ReLU + maxpool(4), MFMA ----------------
__global__ __launch_bounds__(256) void k_conv0m(const float* __restrict__ x,
    const unsigned short* __restrict__ wbf0,
    const float* __restrict__ b0, const float* __restrict__ g0,
    const float* __restrict__ be0, const float* __restrict__ m0,
    const float* __restrict__ v0, float* __restrict__ p)
{
  int b = blockIdx.x, l0 = blockIdx.y * 64;
  __shared__ float xs[71 * 4];
  __shared__ float sc[64], sb[64];
  int tid = threadIdx.x;
  for (int j = tid; j < 71; j += 256) {
    int l = l0 + j;
    float4 xv = (l < LL) ? *(const float4*)(x + ((size_t)b * LL + l) * EMB)
                         : make_float4(0.f, 0.f, 0.f, 0.f);
    *(float4*)(xs + j * 4) = xv;
  }
  if (tid < 64) {
    float s = g0[tid] * rsqrtf(v0[tid] + 1e-5f);
    sc[tid] = s;
    sb[tid] = (b0[tid] - m0[tid]) * s + be0[tid];
  }
  __syncthreads();
  int w = tid >> 6, lane = tid & 63, nl = lane & 15, quad = lane >> 4;
  const float* ap = xs + (w * 16 + nl) * 4 + quad;   // A[m][quad*8+j] = x[l0+m+j][quad]
  short8 af;
  #pragma unroll
  for (int j = 0; j < 8; ++j) af[j] = (short)bfr(ap[j * 4]);
  f32x4 acc[4];
  #pragma unroll
  for (int nt = 0; nt < 4; ++nt) {
    short8 bf = __builtin_bit_cast(short8,
        *(const uint4v*)(wbf0 + ((nt * 16 + nl) * 32 + quad * 8)));
    acc[nt] = (f32x4){0.f, 0.f, 0.f, 0.f};
    acc[nt] = __builtin_amdgcn_mfma_f32_16x16x32_bf16(af, bf, acc[nt], 0, 0, 0);
  }
  int t = (l0 >> 2) + w * 4 + quad;
  if (t < LP) {
    #pragma unroll
    for (int nt = 0; nt < 4; ++nt) {
      int c = nt * 16 + nl;
      float scc = sc[c], sbc = sb[c];
      float mx = -1e30f;
      #pragma unroll
      for (int r = 0; r < 4; ++r) mx = fmaxf(mx, acc[nt][r] * scc + sbc);
      p[((size_t)b * LP + t) * CC + c] = fmaxf(mx, 0.0f);
    }
  }
}

// ---------------- K2: conv1 + BN + ReLU -> x2[b][t][c], MFMA ----------------
__global__ __launch_bounds__(256) void k_conv1m(const float* __restrict__ p,
    const unsigned short* __restrict__ wbf1,
    const float* __restrict__ b1, const float* __restrict__ g1,
    const float* __restrict__ be1, const float* __restrict__ m1,
    const float* __restrict__ v1, float* __restrict__ x2)
{
  int b = blockIdx.x, t0 = blockIdx.y * 64;
  __shared__ float As[71 * 68];
  __shared__ float sc[64], sb[64];
  int tid = threadIdx.x;
  for (int j = tid; j < 71 * 64; j += 256) {
    int col = j >> 6, ci = j & 63;
    int t = t0 + col;
    As[col * 68 + ci] = (t < LP) ? p[((size_t)b * LP + t) * CC + ci] : 0.0f;
  }
  if (tid < 64) {
    float s = g1[tid] * rsqrtf(v1[tid] + 1e-5f);
    sc[tid] = s;
    sb[tid] = (b1[tid] - m1[tid]) * s + be1[tid];
  }
  __syncthreads();
  int w = tid >> 6, lane = tid & 63, nl = lane & 15, quad = lane >> 4;
  const float* ap = As + (w * 16 + nl) * 68;
  f32x4 acc[4];
  #pragma unroll
  for (int nt = 0; nt < 4; ++nt) acc[nt] = (f32x4){0.f, 0.f, 0.f, 0.f};
  for (int ks = 0; ks < 16; ++ks) {
    int ci = ks * 4 + quad;
    short8 af;
    #pragma unroll
    for (int j = 0; j < 8; ++j) af[j] = (short)bfr(ap[j * 68 + ci]);
    #pragma unroll
    for (int nt = 0; nt < 4; ++nt) {
      short8 bf = __builtin_bit_cast(short8,
          *(const uint4v*)(wbf1 + ((size_t)(nt * 16 + nl) * 512 + ci * 8)));
      acc[nt] = __builtin_amdgcn_mfma_f32_16x16x32_bf16(af, bf, acc[nt], 0, 0, 0);
    }
  }
  #pragma unroll
  for (int nt = 0; nt < 4; ++nt) {
    int c = nt * 16 + nl;
    float scc = sc[c], sbc = sb[c];
    #pragma unroll
    for (int r = 0; r < 4; ++r) {
      int t = t0 + w * 16 + quad * 4 + r;
      if (t < TT) x2[((size_t)b * TT + t) * CC + c] = fmaxf(acc[nt][r] * scc + sbc, 0.0f);
    }
  }
}

// ---------------- K3: bi-LSTM via MFMA, block = (16 batches, dir), 4 waves ----------------
// wave w owns hidden slice h0=w*16..w*16+15 for all 4 gate groups (i,f,g,o).
// Per step: gates = x_t@Wih^T + h@Whh^T + bias -> 16 MFMA (K=64 each part).
// h round-trips LDS (bf16, A-frag layout), double-buffered -> 1 barrier/step.
__global__ __launch_bounds__(256) void k_lstm_m(const float* __restrict__ x2,
    const unsigned short* __restrict__ wihbf, const unsigned short* __restrict__ whhbf,
    const float* __restrict__ lbias,
    float* __restrict__ values, float* __restrict__ hT)
{
  int b0 = blockIdx.x * 16;
  int dir = blockIdx.y;
  int tid = threadIdx.x;
  int w = tid >> 6, lane = tid & 63, l15 = lane & 15, quad = lane >> 4;
  int h0 = w * 16;
  const unsigned short* wih = wihbf + dir * 16384;
  const unsigned short* whh = whhbf + dir * 16384;

  // B-fragments (resident whole kernel): [gate][k-step]
  short8 bx[4][2], bh[4][2];
  float bias_v[4];
  #pragma unroll
  for (int g = 0; g < 4; ++g) {
    int row = g * 64 + h0 + l15;
    #pragma unroll
    for (int k = 0; k < 2; ++k) {
      bx[g][k] = __builtin_bit_cast(short8, *(const uint4v*)(wih + row * 64 + k * 32 + quad * 8));
      bh[g][k] = __builtin_bit_cast(short8, *(const uint4v*)(whh + row * 64 + k * 32 + quad * 8));
    }
    bias_v[g] = lbias[dir * 256 + g * 64 + h0 + l15];
  }

  __shared__ unsigned short xs[2][16 * 72];   // [buf][batch][d], stride 72 (pad)
  __shared__ unsigned short hs[2][16 * 72];
  for (int j = tid; j < 16 * 72; j += 256) hs[0][j] = 0;

  // x staging: thread tid loads float4 for (batch bl, dims d4*4..+3)
  int bl = tid >> 4, d4 = tid & 15;
  const float* xrow = x2 + ((size_t)(b0 + bl) * TT) * 64 + d4 * 4;
  // s=0 directly into xs[0]
  {
    int t = dir ? (TT - 1) : 0;
    float4 xv = *(const float4*)(xrow + (size_t)t * 64);
    unsigned lo = bfr(xv.x) | ((unsigned)bfr(xv.y) << 16);
    unsigned hi = bfr(xv.z) | ((unsigned)bfr(xv.w) << 16);
    *(uint2*)(&xs[0][bl * 72 + d4 * 4]) = make_uint2(lo, hi);
  }
  // prefetch regs: xr[s&1] holds x[s] for s = 1, 2
  float4 xr[2];
  {
    int t1 = dir ? (TT - 2) : 1;
    int t2 = dir ? (TT - 3) : 2;
    xr[1] = *(const float4*)(xrow + (size_t)t1 * 64);
    xr[0] = *(const float4*)(xrow + (size_t)t2 * 64);
  }
  __syncthreads();

  float cst[4] = {0.f, 0.f, 0.f, 0.f};
  for (int s = 0; s < TT; ++s) {
    int p = s & 1;
    int t = dir ? (TT - 1 - s) : s;
    // A-fragments from LDS (bf16): x and h, 2 k-steps each
    short8 ax0 = __builtin_bit_cast(short8, *(const uint4v*)(&xs[p][l15 * 72 + 0  + quad * 8]));
    short8 ax1 = __builtin_bit_cast(short8, *(const uint4v*)(&xs[p][l15 * 72 + 32 + quad * 8]));
    short8 ah0 = __builtin_bit_cast(short8, *(const uint4v*)(&hs[p][l15 * 72 + 0  + quad * 8]));
    short8 ah1 = __builtin_bit_cast(short8, *(const uint4v*)(&hs[p][l15 * 72 + 32 + quad * 8]));
    f32x4 acc[4];
    #pragma unroll
    for (int g = 0; g < 4; ++g) {
      acc[g] = (f32x4){bias_v[g], bias_v[g], bias_v[g], bias_v[g]};
      acc[g] = __builtin_amdgcn_mfma_f32_16x16x32_bf16(ax0, bx[g][0], acc[g], 0, 0, 0);
      acc[g] = __builtin_amdgcn_mfma_f32_16x16x32_bf16(ax1, bx[g][1], acc[g], 0, 0, 0);
      acc[g] = __builtin_amdgcn_mfma_f32_16x16x32_bf16(ah0, bh[g][0], acc[g], 0, 0, 0);
      acc[g] = __builtin_amdgcn_mfma_f32_16x16x32_bf16(ah1, bh[g][1], acc[g], 0, 0, 0);
    }
    // stage x for s+1 from prefetch reg; issue load for s+3
    if (s + 1 < TT) {
      float4 xv = xr[(s + 1) & 1];
      unsigned lo = bfr(xv.x) | ((unsigned)bfr(xv.y) << 16);
      unsigned hi = bfr(xv.z) | ((unsigned)bfr(xv.w) << 16);
      *(uint2*)(&xs[1 - p][bl * 72 + d4 * 4]) = make_uint2(lo, hi);
      int sl = (s + 3 < TT) ? (s + 3) : (TT - 1);
      int tl = dir ? (TT - 1 - sl) : sl;
      xr[(s + 1) & 1] = *(const float4*)(xrow + (size_t)tl * 64);
    }
    // gate nonlinearities + state update (4 batches per lane)
    #pragma unroll
    for (int r = 0; r < 4; ++r) {
      float ig = sigf(acc[0][r]);
      float fg = sigf(acc[1][r]);
      float gg = tanhff(acc[2][r]);
      float og = sigf(acc[3][r]);
      cst[r] = fg * cst[r] + ig * gg;
      float hh = og * tanhff(cst[r]);
      int bglob = b0 + quad * 4 + r;
      values[((size_t)bglob * TT + t) * D2 + dir * 64 + h0 + l15] = hh;
      hs[1 - p][(quad * 4 + r) * 72 + h0 + l15] = bfr(hh);
      if (s == TT - 1) hT[((size_t)dir * BB + bglob) * 64 + h0 + l15] = hh;
    }
    __syncthreads();
  }
}

// ---------------- K3b: q2 = h_n @ W2^T + W2_b ----------------
__global__ __launch_bounds__(128) void k_q2(const float* __restrict__ hT,
    const float* __restrict__ W2, const float* __restrict__ W2b,
    float* __restrict__ q2)
{
  int b = blockIdx.x;
  int tid = threadIdx.x;
  __shared__ float4 hn4[32];
  ((float*)hn4)[tid] = hT[(size_t)b * 128 + tid];
  __syncthreads();
  const float4* w4 = (const float4*)(W2 + (size_t)tid * 128);
  float a = W2b[tid];
  #pragma unroll
  for (int j = 0; j < 32; ++j) {
    float4 w = w4[j]; float4 h = hn4[j];
    a += w.x * h.x + w.y * h.y + w.z * h.z + w.w * h.w;
  }
  q2[(size_t)b * 128 + tid] = a;
}

// ---------------- K4: score = tanh(values@W1^T + W1b + q2) @ V^T + Vb ----------------
__global__ __launch_bounds__(256) void k_score(const float* __restrict__ values,
    const float* __restrict__ W1, const float* __restrict__ W1b,
    const float* __restrict__ q2,
    const float* __restrict__ Vw, const float* __restrict__ Vb,
    float* __restrict__ score)
{
  int b = blockIdx.x;
  int t0 = blockIdx.y * 32;
  int tid = threadIdx.x;
  __shared__ float vs[32 * 128];
  __shared__ float us[32 * 128];
  for (int j = tid; j < 32 * 128; j += 256) {
    int tl = j >> 7, d = j & 127;
    int t = t0 + tl;
    vs[j] = (t < TT) ? values[((size_t)b * TT + t) * D2 + d] : 0.0f;
  }
  __syncthreads();
  {
    int d = tid & 127, th = tid >> 7;
    float base = W1b[d] + q2[(size_t)b * 128 + d];
    float acc[16];
    #pragma unroll
    for (int i = 0; i < 16; ++i) acc[i] = 0.0f;
    const float4* w4 = (const float4*)(W1 + (size_t)d * 128);
    for (int k4 = 0; k4 < 32; ++k4) {
      float4 w = w4[k4];
      #pragma unroll
      for (int i = 0; i < 16; ++i) {
        int tl = th + 2 * i;
        float4 v = *(const float4*)(vs + tl * 128 + k4 * 4);
        acc[i] += v.x * w.x + v.y * w.y + v.z * w.z + v.w * w.w;
      }
    }
    #pragma unroll
    for (int i = 0; i < 16; ++i) {
      int tl = th + 2 * i;
      us[tl * 128 + d] = tanhf(acc[i] + base);
    }
  }
  __syncthreads();
  if (tid < NTF) {
    int n = tid;
    float acc[32];
    #pragma unroll
    for (int i = 0; i < 32; ++i) acc[i] = 0.0f;
    const float4* v4 = (const float4*)(Vw + (size_t)n * 128);
    for (int k4 = 0; k4 < 32; ++k4) {
      float4 w = v4[k4];
      #pragma unroll
      for (int tl = 0; tl < 32; ++tl) {
        float4 u = *(const float4*)(us + tl * 128 + k4 * 4);
        acc[tl] += u.x * w.x + u.y * w.y + u.z * w.z + u.w * w.w;
      }
    }
    float vb = Vb[n];
    for (int tl = 0; tl < 32; ++tl) {
      int t = t0 + tl;
      if (t < TT) score[((size_t)b * TT + t) * NTF + n] = acc[tl] + vb;
    }
  }
}

// ---------------- K5: softmax over t (stores unnormalized exp + 1/sum) ----------------
__global__ __launch_bounds__(256) void k_softmax(float* __restrict__ score,
    float* __restrict__ sinv)
{
  int b = blockIdx.x;
  int n = threadIdx.x;
  if (n >= NTF) return;
  size_t base = (size_t)b * TT * NTF + n;
  float m = -1e30f;
  for (int t = 0; t < TT; ++t) m = fmaxf(m, score[base + (size_t)t * NTF]);
  float s = 0.0f;
  for (int t = 0; t < TT; ++t) {
    float e = __expf(score[base + (size_t)t * NTF] - m);
    score[base + (size_t)t * NTF] = e;
    s += e;
  }
  sinv[(size_t)b * NTF + n] = 1.0f / s;
}

// ---------------- K6: context[b][n][d] = (sum_t e[t,n] * values[t,d]) * sinv ----------------
__global__ __launch_bounds__(256) void k_context(const float* __restrict__ values,
    const float* __restrict__ score, const float* __restrict__ sinv,
    float* __restrict__ ctx)
{
  int b = blockIdx.x;
  int n0 = blockIdx.y * 16;
  int tid = threadIdx.x;
  __shared__ float vls[32 * 128];
  __shared__ float als[32 * 16];
  int nl = tid >> 4, dg = tid & 15;
  float acc[8];
  #pragma unroll
  for (int i = 0; i < 8; ++i) acc[i] = 0.0f;
  for (int tc = 0; tc < TT; tc += 32) {
    __syncthreads();
    for (int j = tid; j < 32 * 128; j += 256) {
      int tl = j >> 7, d = j & 127;
      int t = tc + tl;
      vls[j] = (t < TT) ? values[((size_t)b * TT + t) * D2 + d] : 0.0f;
    }
    for (int j = tid; j < 512; j += 256) {
      int tl = j >> 4, nn = j & 15;
      int t = tc + tl, n = n0 + nn;
      als[j] = (t < TT && n < NTF) ? score[((size_t)b * TT + t) * NTF + n] : 0.0f;
    }
    __syncthreads();
    #pragma unroll
    for (int tl = 0; tl < 32; ++tl) {
      float a = als[tl * 16 + nl];
      const float4* v4 = (const float4*)(vls + tl * 128 + dg * 8);
      float4 v0 = v4[0], v1 = v4[1];
      acc[0] += a * v0.x; acc[1] += a * v0.y; acc[2] += a * v0.z; acc[3] += a * v0.w;
      acc[4] += a * v1.x; acc[5] += a * v1.y; acc[6] += a * v1.z; acc[7] += a * v1.w;
    }
  }
  int n = n0 + nl;
  if (n < NTF) {
    float rs = sinv[(size_t)b * NTF + n];
    float4 o0 = make_float4(acc[0] * rs, acc[1] * rs, acc[2] * rs, acc[3] * rs);
    float4 o1 = make_float4(acc[4] * rs, acc[5] * rs, acc[6] * rs, acc[7] * rs);
    float4* op = (float4*)(ctx + ((size_t)b * NTF + n) * D2 + dg * 8);
    op[0] = o0; op[1] = o1;
  }
}

// ---------------- K7: per-TF heads ----------------
__global__ __launch_bounds__(256) void k_heads(const float* __restrict__ ctx,
    const float* __restrict__ fc1w, const float* __restrict__ fc1b,
    const float* __restrict__ fc2w, const float* __restrict__ fc2b,
    float* __restrict__ out)
{
  int n = blockIdx.x;
  int bq = blockIdx.y;
  int tid = threadIdx.x;
  int o = tid & 63, w = tid >> 6;
  __shared__ float ctxs[4 * 128];
  float4 fr[32];
  const float4* fp = (const float4*)(fc1w + ((size_t)n * 64 + o) * 128);
  #pragma unroll
  for (int j = 0; j < 32; ++j) fr[j] = fp[j];
  float f1bv = fc1b[n * 64 + o];
  float f2 = fc2w[n * 64 + o];
  float f2b = fc2b[n];
  for (int i = 0; i < 16; ++i) {
    int bbase = bq * 64 + i * 4;
    __syncthreads();
    for (int j = tid; j < 512; j += 256) {
      int ww = j >> 7, k = j & 127;
      ctxs[j] = ctx[((size_t)(bbase + ww) * NTF + n) * D2 + k];
    }
    __syncthreads();
    float a = f1bv;
    const float4* c4 = (const float4*)(ctxs + w * 128);
    #pragma unroll
    for (int j = 0; j < 32; ++j) {
      float4 cv = c4[j];
      float4 fv = fr[j];
      a += cv.x * fv.x + cv.y * fv.y + cv.z * fv.z + cv.w * fv.w;
    }
    float part = fmaxf(a, 0.0f) * f2;
    #pragma unroll
    for (int off = 32; off > 0; off >>= 1)
      part += __shfl_down(part, off, 64);
    if (o == 0) out[(size_t)(bbase + w) * NTF + n] = part + f2b;
  }
}

extern "C" void kernel_launch(void* const* d_in, const int* in_sizes, int n_in,
                              void* d_out, int out_size, void* d_ws, size_t ws_size,
                              hipStream_t stream)
{
  const float* x    = (const float*)d_in[0];
  const float* c0w  = (const float*)d_in[1];
  const float* c0b  = (const float*)d_in[2];
  const float* g0   = (const float*)d_in[3];
  const float* be0  = (const float*)d_in[4];
  const float* m0   = (const float*)d_in[5];
  const float* v0   = (const float*)d_in[6];
  const float* c1w  = (const float*)d_in[7];
  const float* c1b  = (const float*)d_in[8];
  const float* g1   = (const float*)d_in[9];
  const float* be1  = (const float*)d_in[10];
  const float* m1   = (const float*)d_in[11];
  const float* v1   = (const float*)d_in[12];
  const float* wihf = (const float*)d_in[13];
  const float* whhf = (const float*)d_in[14];
  const float* bihf = (const float*)d_in[15];
  const float* bhhf = (const float*)d_in[16];
  const float* wihb = (const float*)d_in[17];
  const float* whhb = (const float*)d_in[18];
  const float* bihb = (const float*)d_in[19];
  const float* bhhb = (const float*)d_in[20];
  const float* W1w  = (const float*)d_in[21];
  const float* W1b  = (const float*)d_in[22];
  const float* W2w  = (const float*)d_in[23];
  const float* W2b  = (const float*)d_in[24];
  const float* Vw   = (const float*)d_in[25];
  const float* Vb   = (const float*)d_in[26];
  const float* f1w  = (const float*)d_in[27];
  const float* f1b  = (const float*)d_in[28];
  const float* f2w  = (const float*)d_in[29];
  const float* f2b  = (const float*)d_in[30];

  float* ws = (float*)d_ws;
  float* score  = ws;                    // 512*247*200 = 25,292,800
  float* p      = ws;                    // [b][t][c] 512*254*64
  float* x2     = ws + 8323072;          // 512*247*64
  float* values = ws + 25292800;         // 512*247*128
  float* hT     = ws + 41480192;         // 2*512*64
  float* q2     = ws + 41545728;         // 512*128
  float* sinv   = ws + 41611264;         // 512*200
  float* ctx    = ws + 41713664;         // 512*200*128 (ends 54,820,864)
  unsigned short* wbf0  = (unsigned short*)(ws + 54820864);  // 2048 bf16
  unsigned short* wbf1  = (unsigned short*)(ws + 54821888);  // 32768 bf16
  unsigned short* wihbf = (unsigned short*)(ws + 54838272);  // 2*16384 bf16
  unsigned short* whhbf = (unsigned short*)(ws + 54854656);  // 2*16384 bf16
  float* lbias          = ws + 54871040;                     // 2*256 f32
  float* out    = (float*)d_out;

  k_cvt<<<dim3(128), 256, 0, stream>>>(c0w, c1w, wihf, whhf, wihb, whhb,
                                       bihf, bhhf, bihb, bhhb,
                                       wbf0, wbf1, wihbf, whhbf, lbias);
  k_conv0m<<<dim3(BB, 16), 256, 0, stream>>>(x, wbf0, c0b, g0, be0, m0, v0, p);
  k_conv1m<<<dim3(BB, 4), 256, 0, stream>>>(p, wbf1, c1b, g1, be1, m1, v1, x2);
  k_lstm_m<<<dim3(BB / 16, 2), 256, 0, stream>>>(x2, wihbf, whhbf, lbias, values, hT);
  k_q2<<<dim3(BB), 128, 0, stream>>>(hT, W2w, W2b, q2);
  k_score<<<dim3(BB, 8), 256, 0, stream>>>(values, W1w, W1b, q2, Vw, Vb, score);
  k_softmax<<<dim3(BB), 256, 0, stream>>>(score, sinv);
  k_context<<<dim3(BB, 13), 256, 0, stream>>>(values, score, sinv, ctx);
  k_heads<<<dim3(NTF, 8), 256, 0, stream>>>(ctx, f1w, f1b, f2w, f2b, out);
}

// Round 4
// 994.723 us; speedup vs baseline: 2.1589x; 1.3014x over previous
//
#include <hip/hip_runtime.h>
#include <math.h>

#define BB 512
#define LL 1024
#define EMB 4
#define CC 64
#define NTF 200
#define TT 247      // seq len after conv1
#define LP 254      // after pool
#define D2 128

typedef __attribute__((ext_vector_type(8))) short short8;
typedef __attribute__((ext_vector_type(4))) float f32x4;
typedef __attribute__((ext_vector_type(4))) unsigned int uint4v;

__device__ __forceinline__ float sigf(float x) { return 1.0f / (1.0f + __expf(-x)); }
__device__ __forceinline__ float tanhff(float x) {
  return 1.0f - 2.0f / (__expf(2.0f * x) + 1.0f);
}

// f32 -> bf16 round-to-nearest-even (finite inputs)
__device__ __forceinline__ unsigned short bfr(float f) {
  unsigned u = __builtin_bit_cast(unsigned, f);
  u += 0x7fffu + ((u >> 16) & 1u);
  return (unsigned short)(u >> 16);
}

// ---------------- K0: convert weights to bf16 in ws + lstm bias sums ----------------
__global__ __launch_bounds__(256) void k_cvt(const float* __restrict__ w0,
    const float* __restrict__ w1,
    const float* __restrict__ wihf, const float* __restrict__ whhf,
    const float* __restrict__ wihb, const float* __restrict__ whhb,
    const float* __restrict__ bihf, const float* __restrict__ bhhf,
    const float* __restrict__ bihb, const float* __restrict__ bhhb,
    const float* __restrict__ W1w, const float* __restrict__ Vw,
    unsigned short* __restrict__ wbf0, unsigned short* __restrict__ wbf1,
    unsigned short* __restrict__ wihbf, unsigned short* __restrict__ whhbf,
    float* __restrict__ lbias,
    unsigned short* __restrict__ W1bf, unsigned short* __restrict__ Vbf)
{
  int i = blockIdx.x * 256 + threadIdx.x;   // grid 128*256 = 32768
  if (i < 2048) wbf0[i] = bfr(w0[i]);
  if (i < 32768) wbf1[i] = bfr(w1[i]);
  if (i < 16384) {
    wihbf[i] = bfr(wihf[i]);
    wihbf[16384 + i] = bfr(wihb[i]);
    whhbf[i] = bfr(whhf[i]);
    whhbf[16384 + i] = bfr(whhb[i]);
    W1bf[i] = bfr(W1w[i]);
  }
  if (i < 26624) {                           // Vbf padded to 208 rows
    int row = i >> 7;
    Vbf[i] = (row < NTF) ? bfr(Vw[i]) : (unsigned short)0;
  }
  if (i < 256) {
    lbias[i] = bihf[i] + bhhf[i];
    lbias[256 + i] = bihb[i] + bhhb[i];
  }
}

// ---------------- K1: conv0 + BN + ReLU + maxpool(4), MFMA ----------------
__global__ __launch_bounds__(256) void k_conv0m(const float* __restrict__ x,
    const unsigned short* __restrict__ wbf0,
    const float* __restrict__ b0, const float* __restrict__ g0,
    const float* __restrict__ be0, const float* __restrict__ m0,
    const float* __restrict__ v0, float* __restrict__ p)
{
  int b = blockIdx.x, l0 = blockIdx.y * 64;
  __shared__ float xs[71 * 4];
  __shared__ float sc[64], sb[64];
  int tid = threadIdx.x;
  for (int j = tid; j < 71; j += 256) {
    int l = l0 + j;
    float4 xv = (l < LL) ? *(const float4*)(x + ((size_t)b * LL + l) * EMB)
                         : make_float4(0.f, 0.f, 0.f, 0.f);
    *(float4*)(xs + j * 4) = xv;
  }
  if (tid < 64) {
    float s = g0[tid] * rsqrtf(v0[tid] + 1e-5f);
    sc[tid] = s;
    sb[tid] = (b0[tid] - m0[tid]) * s + be0[tid];
  }
  __syncthreads();
  int w = tid >> 6, lane = tid & 63, nl = lane & 15, quad = lane >> 4;
  const float* ap = xs + (w * 16 + nl) * 4 + quad;
  short8 af;
  #pragma unroll
  for (int j = 0; j < 8; ++j) af[j] = (short)bfr(ap[j * 4]);
  f32x4 acc[4];
  #pragma unroll
  for (int nt = 0; nt < 4; ++nt) {
    short8 bf = __builtin_bit_cast(short8,
        *(const uint4v*)(wbf0 + ((nt * 16 + nl) * 32 + quad * 8)));
    acc[nt] = (f32x4){0.f, 0.f, 0.f, 0.f};
    acc[nt] = __builtin_amdgcn_mfma_f32_16x16x32_bf16(af, bf, acc[nt], 0, 0, 0);
  }
  int t = (l0 >> 2) + w * 4 + quad;
  if (t < LP) {
    #pragma unroll
    for (int nt = 0; nt < 4; ++nt) {
      int c = nt * 16 + nl;
      float scc = sc[c], sbc = sb[c];
      float mx = -1e30f;
      #pragma unroll
      for (int r = 0; r < 4; ++r) mx = fmaxf(mx, acc[nt][r] * scc + sbc);
      p[((size_t)b * LP + t) * CC + c] = fmaxf(mx, 0.0f);
    }
  }
}

// ---------------- K2: conv1 + BN + ReLU -> x2[b][t][c], MFMA ----------------
__global__ __launch_bounds__(256) void k_conv1m(const float* __restrict__ p,
    const unsigned short* __restrict__ wbf1,
    const float* __restrict__ b1, const float* __restrict__ g1,
    const float* __restrict__ be1, const float* __restrict__ m1,
    const float* __restrict__ v1, float* __restrict__ x2)
{
  int b = blockIdx.x, t0 = blockIdx.y * 64;
  __shared__ float As[71 * 68];
  __shared__ float sc[64], sb[64];
  int tid = threadIdx.x;
  for (int j = tid; j < 71 * 64; j += 256) {
    int col = j >> 6, ci = j & 63;
    int t = t0 + col;
    As[col * 68 + ci] = (t < LP) ? p[((size_t)b * LP + t) * CC + ci] : 0.0f;
  }
  if (tid < 64) {
    float s = g1[tid] * rsqrtf(v1[tid] + 1e-5f);
    sc[tid] = s;
    sb[tid] = (b1[tid] - m1[tid]) * s + be1[tid];
  }
  __syncthreads();
  int w = tid >> 6, lane = tid & 63, nl = lane & 15, quad = lane >> 4;
  const float* ap = As + (w * 16 + nl) * 68;
  f32x4 acc[4];
  #pragma unroll
  for (int nt = 0; nt < 4; ++nt) acc[nt] = (f32x4){0.f, 0.f, 0.f, 0.f};
  for (int ks = 0; ks < 16; ++ks) {
    int ci = ks * 4 + quad;
    short8 af;
    #pragma unroll
    for (int j = 0; j < 8; ++j) af[j] = (short)bfr(ap[j * 68 + ci]);
    #pragma unroll
    for (int nt = 0; nt < 4; ++nt) {
      short8 bf = __builtin_bit_cast(short8,
          *(const uint4v*)(wbf1 + ((size_t)(nt * 16 + nl) * 512 + ci * 8)));
      acc[nt] = __builtin_amdgcn_mfma_f32_16x16x32_bf16(af, bf, acc[nt], 0, 0, 0);
    }
  }
  #pragma unroll
  for (int nt = 0; nt < 4; ++nt) {
    int c = nt * 16 + nl;
    float scc = sc[c], sbc = sb[c];
    #pragma unroll
    for (int r = 0; r < 4; ++r) {
      int t = t0 + w * 16 + quad * 4 + r;
      if (t < TT) x2[((size_t)b * TT + t) * CC + c] = fmaxf(acc[nt][r] * scc + sbc, 0.0f);
    }
  }
}

// ---------------- K3: bi-LSTM via MFMA; values output in bf16 ----------------
__global__ __launch_bounds__(256) void k_lstm_m(const float* __restrict__ x2,
    const unsigned short* __restrict__ wihbf, const unsigned short* __restrict__ whhbf,
    const float* __restrict__ lbias,
    unsigned short* __restrict__ values, float* __restrict__ hT)
{
  int b0 = blockIdx.x * 16;
  int dir = blockIdx.y;
  int tid = threadIdx.x;
  int w = tid >> 6, lane = tid & 63, l15 = lane & 15, quad = lane >> 4;
  int h0 = w * 16;
  const unsigned short* wih = wihbf + dir * 16384;
  const unsigned short* whh = whhbf + dir * 16384;

  short8 bx[4][2], bh[4][2];
  float bias_v[4];
  #pragma unroll
  for (int g = 0; g < 4; ++g) {
    int row = g * 64 + h0 + l15;
    #pragma unroll
    for (int k = 0; k < 2; ++k) {
      bx[g][k] = __builtin_bit_cast(short8, *(const uint4v*)(wih + row * 64 + k * 32 + quad * 8));
      bh[g][k] = __builtin_bit_cast(short8, *(const uint4v*)(whh + row * 64 + k * 32 + quad * 8));
    }
    bias_v[g] = lbias[dir * 256 + g * 64 + h0 + l15];
  }

  __shared__ unsigned short xs[2][16 * 72];
  __shared__ unsigned short hs[2][16 * 72];
  for (int j = tid; j < 16 * 72; j += 256) hs[0][j] = 0;

  int bl = tid >> 4, d4 = tid & 15;
  const float* xrow = x2 + ((size_t)(b0 + bl) * TT) * 64 + d4 * 4;
  {
    int t = dir ? (TT - 1) : 0;
    float4 xv = *(const float4*)(xrow + (size_t)t * 64);
    unsigned lo = bfr(xv.x) | ((unsigned)bfr(xv.y) << 16);
    unsigned hi = bfr(xv.z) | ((unsigned)bfr(xv.w) << 16);
    *(uint2*)(&xs[0][bl * 72 + d4 * 4]) = make_uint2(lo, hi);
  }
  float4 xr[2];
  {
    int t1 = dir ? (TT - 2) : 1;
    int t2 = dir ? (TT - 3) : 2;
    xr[1] = *(const float4*)(xrow + (size_t)t1 * 64);
    xr[0] = *(const float4*)(xrow + (size_t)t2 * 64);
  }
  __syncthreads();

  float cst[4] = {0.f, 0.f, 0.f, 0.f};
  for (int s = 0; s < TT; ++s) {
    int p = s & 1;
    int t = dir ? (TT - 1 - s) : s;
    short8 ax0 = __builtin_bit_cast(short8, *(const uint4v*)(&xs[p][l15 * 72 + 0  + quad * 8]));
    short8 ax1 = __builtin_bit_cast(short8, *(const uint4v*)(&xs[p][l15 * 72 + 32 + quad * 8]));
    short8 ah0 = __builtin_bit_cast(short8, *(const uint4v*)(&hs[p][l15 * 72 + 0  + quad * 8]));
    short8 ah1 = __builtin_bit_cast(short8, *(const uint4v*)(&hs[p][l15 * 72 + 32 + quad * 8]));
    f32x4 acc[4];
    #pragma unroll
    for (int g = 0; g < 4; ++g) {
      acc[g] = (f32x4){bias_v[g], bias_v[g], bias_v[g], bias_v[g]};
      acc[g] = __builtin_amdgcn_mfma_f32_16x16x32_bf16(ax0, bx[g][0], acc[g], 0, 0, 0);
      acc[g] = __builtin_amdgcn_mfma_f32_16x16x32_bf16(ax1, bx[g][1], acc[g], 0, 0, 0);
      acc[g] = __builtin_amdgcn_mfma_f32_16x16x32_bf16(ah0, bh[g][0], acc[g], 0, 0, 0);
      acc[g] = __builtin_amdgcn_mfma_f32_16x16x32_bf16(ah1, bh[g][1], acc[g], 0, 0, 0);
    }
    if (s + 1 < TT) {
      float4 xv = xr[(s + 1) & 1];
      unsigned lo = bfr(xv.x) | ((unsigned)bfr(xv.y) << 16);
      unsigned hi = bfr(xv.z) | ((unsigned)bfr(xv.w) << 16);
      *(uint2*)(&xs[1 - p][bl * 72 + d4 * 4]) = make_uint2(lo, hi);
      int sl = (s + 3 < TT) ? (s + 3) : (TT - 1);
      int tl = dir ? (TT - 1 - sl) : sl;
      xr[(s + 1) & 1] = *(const float4*)(xrow + (size_t)tl * 64);
    }
    #pragma unroll
    for (int r = 0; r < 4; ++r) {
      float ig = sigf(acc[0][r]);
      float fg = sigf(acc[1][r]);
      float gg = tanhff(acc[2][r]);
      float og = sigf(acc[3][r]);
      cst[r] = fg * cst[r] + ig * gg;
      float hh = og * tanhff(cst[r]);
      int bglob = b0 + quad * 4 + r;
      unsigned short hbf = bfr(hh);
      values[((size_t)bglob * TT + t) * D2 + dir * 64 + h0 + l15] = hbf;
      hs[1 - p][(quad * 4 + r) * 72 + h0 + l15] = hbf;
      if (s == TT - 1) hT[((size_t)dir * BB + bglob) * 64 + h0 + l15] = hh;
    }
    __syncthreads();
  }
}

// ---------------- K3b: q2 = h_n @ W2^T + W2_b ----------------
__global__ __launch_bounds__(128) void k_q2(const float* __restrict__ hT,
    const float* __restrict__ W2, const float* __restrict__ W2b,
    float* __restrict__ q2)
{
  int b = blockIdx.x;
  int tid = threadIdx.x;
  __shared__ float4 hn4[32];
  ((float*)hn4)[tid] = hT[(size_t)b * 128 + tid];
  __syncthreads();
  const float4* w4 = (const float4*)(W2 + (size_t)tid * 128);
  float a = W2b[tid];
  #pragma unroll
  for (int j = 0; j < 32; ++j) {
    float4 w = w4[j]; float4 h = hn4[j];
    a += w.x * h.x + w.y * h.y + w.z * h.z + w.w * h.w;
  }
  q2[(size_t)b * 128 + tid] = a;
}

// ---------------- K4: score via MFMA ----------------
// GEMM1: u = tanh(values@W1^T + W1b + q2)  (M=64 t, N=128, K=128)
// GEMM2: score = u @ V^T + Vb              (M=64 t, N=208 pad, K=128)
__global__ __launch_bounds__(256) void k_score_m(const unsigned short* __restrict__ vbf,
    const unsigned short* __restrict__ W1bf, const float* __restrict__ W1b,
    const float* __restrict__ q2, const unsigned short* __restrict__ Vbf,
    const float* __restrict__ Vb, float* __restrict__ score)
{
  int b = blockIdx.x, t0 = blockIdx.y * 64;
  int tid = threadIdx.x, w = tid >> 6, lane = tid & 63, l15 = lane & 15, quad = lane >> 4;
  __shared__ unsigned short us[64 * 136];   // u tile bf16, stride 136 (272B, 16B-aligned)
  // A-frags straight from global bf16 values (row-major [t][d] == A-frag layout)
  const unsigned short* arow = vbf + ((size_t)b * TT + t0 + w * 16 + l15) * 128;
  short8 ax[4];
  #pragma unroll
  for (int ks = 0; ks < 4; ++ks)
    ax[ks] = __builtin_bit_cast(short8, *(const uint4v*)(arow + ks * 32 + quad * 8));
  #pragma unroll
  for (int nt = 0; nt < 8; ++nt) {
    int n = nt * 16 + l15;
    float base = W1b[n] + q2[(size_t)b * 128 + n];
    f32x4 acc = (f32x4){base, base, base, base};
    #pragma unroll
    for (int ks = 0; ks < 4; ++ks) {
      short8 bf = __builtin_bit_cast(short8,
          *(const uint4v*)(W1bf + (size_t)n * 128 + ks * 32 + quad * 8));
      acc = __builtin_amdgcn_mfma_f32_16x16x32_bf16(ax[ks], bf, acc, 0, 0, 0);
    }
    #pragma unroll
    for (int r = 0; r < 4; ++r)
      us[(w * 16 + quad * 4 + r) * 136 + nt * 16 + l15] = bfr(tanhf(acc[r]));
  }
  __syncthreads();
  short8 au[4];
  #pragma unroll
  for (int ks = 0; ks < 4; ++ks)
    au[ks] = __builtin_bit_cast(short8, *(const uint4v*)(&us[(w * 16 + l15) * 136 + ks * 32 + quad * 8]));
  for (int nt2 = 0; nt2 < 13; ++nt2) {
    int n = nt2 * 16 + l15;
    float b2 = (n < NTF) ? Vb[n] : 0.0f;
    f32x4 a2 = (f32x4){b2, b2, b2, b2};
    #pragma unroll
    for (int ks = 0; ks < 4; ++ks) {
      short8 bf = __builtin_bit_cast(short8,
          *(const uint4v*)(Vbf + (size_t)n * 128 + ks * 32 + quad * 8));
      a2 = __builtin_amdgcn_mfma_f32_16x16x32_bf16(au[ks], bf, a2, 0, 0, 0);
    }
    #pragma unroll
    for (int r = 0; r < 4; ++r) {
      int t = t0 + w * 16 + quad * 4 + r;
      if (t < TT && n < NTF) score[((size_t)b * TT + t) * NTF + n] = a2[r];
    }
  }
}

// ---------------- K5: softmax over t (stores unnormalized exp + 1/sum) ----------------
__global__ __launch_bounds__(256) void k_softmax(float* __restrict__ score,
    float* __restrict__ sinv)
{
  int b = blockIdx.x;
  int n = threadIdx.x;
  if (n >= NTF) return;
  size_t base = (size_t)b * TT * NTF + n;
  float m = -1e30f;
  for (int t = 0; t < TT; ++t) m = fmaxf(m, score[base + (size_t)t * NTF]);
  float s = 0.0f;
  for (int t = 0; t < TT; ++t) {
    float e = __expf(score[base + (size_t)t * NTF] - m);
    score[base + (size_t)t * NTF] = e;
    s += e;
  }
  sinv[(size_t)b * NTF + n] = 1.0f / s;
}

// ---------------- K6: context via MFMA ----------------
// C = aw^T @ values per b: M=208(n pad), N=128(d), K=256(t pad). Block per b.
__global__ __launch_bounds__(256) void k_ctx_m(const unsigned short* __restrict__ vbf,
    const float* __restrict__ score, const float* __restrict__ sinv,
    float* __restrict__ ctx)
{
  int b = blockIdx.x;
  int tid = threadIdx.x, w = tid >> 6, lane = tid & 63, l15 = lane & 15, quad = lane >> 4;
  __shared__ unsigned short ascore[208 * 40];  // [n][t-local], stride 40 (80B, 16B-aligned)
  __shared__ unsigned short bval[128 * 40];    // [d][t-local]
  __shared__ float sls[208];
  for (int j = tid; j < 208; j += 256) sls[j] = (j < NTF) ? sinv[(size_t)b * NTF + j] : 0.0f;

  f32x4 acc[4][8];
  #pragma unroll
  for (int i = 0; i < 4; ++i)
    #pragma unroll
    for (int nt = 0; nt < 8; ++nt) acc[i][nt] = (f32x4){0.f, 0.f, 0.f, 0.f};

  for (int ch = 0; ch < 8; ++ch) {
    int tc = ch * 32;
    __syncthreads();
    // stage exp-score transposed: ascore[n][tl]
    for (int j = tid; j < 32 * 256; j += 256) {
      int tl = j >> 8, n = j & 255;
      if (n < 208) {
        int t = tc + tl;
        float v = (n < NTF && t < TT) ? score[((size_t)b * TT + t) * NTF + n] : 0.0f;
        ascore[n * 40 + tl] = bfr(v);
      }
    }
    // stage values transposed: bval[d][tl]
    for (int j = tid; j < 32 * 64; j += 256) {
      int tl = j >> 6, d2 = j & 63;
      int t = tc + tl;
      unsigned v = (t < TT) ? *(const unsigned*)(vbf + ((size_t)b * TT + t) * D2 + d2 * 2) : 0u;
      bval[(d2 * 2) * 40 + tl] = (unsigned short)(v & 0xffffu);
      bval[(d2 * 2 + 1) * 40 + tl] = (unsigned short)(v >> 16);
    }
    __syncthreads();
    short8 bv[8];
    #pragma unroll
    for (int nt = 0; nt < 8; ++nt)
      bv[nt] = __builtin_bit_cast(short8, *(const uint4v*)(&bval[(nt * 16 + l15) * 40 + quad * 8]));
    #pragma unroll
    for (int i = 0; i < 4; ++i) {
      int mt = w + 4 * i;
      if (mt < 13) {
        short8 au = __builtin_bit_cast(short8, *(const uint4v*)(&ascore[(mt * 16 + l15) * 40 + quad * 8]));
        #pragma unroll
        for (int nt = 0; nt < 8; ++nt)
          acc[i][nt] = __builtin_amdgcn_mfma_f32_16x16x32_bf16(au, bv[nt], acc[i][nt], 0, 0, 0);
      }
    }
  }
  #pragma unroll
  for (int i = 0; i < 4; ++i) {
    int mt = w + 4 * i;
    if (mt < 13) {
      #pragma unroll
      for (int r = 0; r < 4; ++r) {
        int n = mt * 16 + quad * 4 + r;
        if (n < NTF) {
          float rs = sls[n];
          #pragma unroll
          for (int nt = 0; nt < 8; ++nt) {
            int d = nt * 16 + l15;
            ctx[((size_t)b * NTF + n) * D2 + d] = acc[i][nt][r] * rs;
          }
        }
      }
    }
  }
}

// ---------------- K7: per-TF heads ----------------
__global__ __launch_bounds__(256) void k_heads(const float* __restrict__ ctx,
    const float* __restrict__ fc1w, const float* __restrict__ fc1b,
    const float* __restrict__ fc2w, const float* __restrict__ fc2b,
    float* __restrict__ out)
{
  int n = blockIdx.x;
  int bq = blockIdx.y;
  int tid = threadIdx.x;
  int o = tid & 63, w = tid >> 6;
  __shared__ float ctxs[4 * 128];
  float4 fr[32];
  const float4* fp = (const float4*)(fc1w + ((size_t)n * 64 + o) * 128);
  #pragma unroll
  for (int j = 0; j < 32; ++j) fr[j] = fp[j];
  float f1bv = fc1b[n * 64 + o];
  float f2 = fc2w[n * 64 + o];
  float f2b = fc2b[n];
  for (int i = 0; i < 16; ++i) {
    int bbase = bq * 64 + i * 4;
    __syncthreads();
    for (int j = tid; j < 512; j += 256) {
      int ww = j >> 7, k = j & 127;
      ctxs[j] = ctx[((size_t)(bbase + ww) * NTF + n) * D2 + k];
    }
    __syncthreads();
    float a = f1bv;
    const float4* c4 = (const float4*)(ctxs + w * 128);
    #pragma unroll
    for (int j = 0; j < 32; ++j) {
      float4 cv = c4[j];
      float4 fv = fr[j];
      a += cv.x * fv.x + cv.y * fv.y + cv.z * fv.z + cv.w * fv.w;
    }
    float part = fmaxf(a, 0.0f) * f2;
    #pragma unroll
    for (int off = 32; off > 0; off >>= 1)
      part += __shfl_down(part, off, 64);
    if (o == 0) out[(size_t)(bbase + w) * NTF + n] = part + f2b;
  }
}

extern "C" void kernel_launch(void* const* d_in, const int* in_sizes, int n_in,
                              void* d_out, int out_size, void* d_ws, size_t ws_size,
                              hipStream_t stream)
{
  const float* x    = (const float*)d_in[0];
  const float* c0w  = (const float*)d_in[1];
  const float* c0b  = (const float*)d_in[2];
  const float* g0   = (const float*)d_in[3];
  const float* be0  = (const float*)d_in[4];
  const float* m0   = (const float*)d_in[5];
  const float* v0   = (const float*)d_in[6];
  const float* c1w  = (const float*)d_in[7];
  const float* c1b  = (const float*)d_in[8];
  const float* g1   = (const float*)d_in[9];
  const float* be1  = (const float*)d_in[10];
  const float* m1   = (const float*)d_in[11];
  const float* v1   = (const float*)d_in[12];
  const float* wihf = (const float*)d_in[13];
  const float* whhf = (const float*)d_in[14];
  const float* bihf = (const float*)d_in[15];
  const float* bhhf = (const float*)d_in[16];
  const float* wihb = (const float*)d_in[17];
  const float* whhb = (const float*)d_in[18];
  const float* bihb = (const float*)d_in[19];
  const float* bhhb = (const float*)d_in[20];
  const float* W1w  = (const float*)d_in[21];
  const float* W1b  = (const float*)d_in[22];
  const float* W2w  = (const float*)d_in[23];
  const float* W2b  = (const float*)d_in[24];
  const float* Vw   = (const float*)d_in[25];
  const float* Vb   = (const float*)d_in[26];
  const float* f1w  = (const float*)d_in[27];
  const float* f1b  = (const float*)d_in[28];
  const float* f2w  = (const float*)d_in[29];
  const float* f2b  = (const float*)d_in[30];

  float* ws = (float*)d_ws;
  // layout (f32 offsets); p/x2 overlap score (dead before k_score_m writes)
  float* score  = ws;                         // 25,292,800 f32
  float* p      = ws;                         // 8,323,072
  float* x2     = ws + 8323072;               // 8,093,696 (ends 16,416,768)
  unsigned short* vbf = (unsigned short*)(ws + 25292800);  // 16,187,392 bf16 (+slack)
  float* hT     = ws + 33387520;              // 65,536
  float* q2     = ws + 33453056;              // 65,536
  float* sinv   = ws + 33518592;              // 102,400
  float* ctx    = ws + 33620992;              // 13,107,200 (ends 46,728,192)
  unsigned short* wbf0  = (unsigned short*)(ws + 46728192);  // 2048
  unsigned short* wbf1  = (unsigned short*)(ws + 46729216);  // 32768
  unsigned short* wihbf = (unsigned short*)(ws + 46745600);  // 32768
  unsigned short* whhbf = (unsigned short*)(ws + 46761984);  // 32768
  float* lbias          = ws + 46778368;                     // 512
  unsigned short* W1bf  = (unsigned short*)(ws + 46778880);  // 16384
  unsigned short* Vbf   = (unsigned short*)(ws + 46787072);  // 26624
  float* out    = (float*)d_out;

  k_cvt<<<dim3(128), 256, 0, stream>>>(c0w, c1w, wihf, whhf, wihb, whhb,
                                       bihf, bhhf, bihb, bhhb, W1w, Vw,
                                       wbf0, wbf1, wihbf, whhbf, lbias, W1bf, Vbf);
  k_conv0m<<<dim3(BB, 16), 256, 0, stream>>>(x, wbf0, c0b, g0, be0, m0, v0, p);
  k_conv1m<<<dim3(BB, 4), 256, 0, stream>>>(p, wbf1, c1b, g1, be1, m1, v1, x2);
  k_lstm_m<<<dim3(BB / 16, 2), 256, 0, stream>>>(x2, wihbf, whhbf, lbias, vbf, hT);
  k_q2<<<dim3(BB), 128, 0, stream>>>(hT, W2w, W2b, q2);
  k_score_m<<<dim3(BB, 4), 256, 0, stream>>>(vbf, W1bf, W1b, q2, Vbf, Vb, score);
  k_softmax<<<dim3(BB), 256, 0, stream>>>(score, sinv);
  k_ctx_m<<<dim3(BB), 256, 0, stream>>>(vbf, score, sinv, ctx);
  k_heads<<<dim3(NTF, 8), 256, 0, stream>>>(ctx, f1w, f1b, f2w, f2b, out);
}